// Round 5
// baseline (793.062 us; speedup 1.0000x reference)
//
#include <hip/hip_runtime.h>
#include <math.h>

// Problem constants (match reference)
#define BB 4
#define TT 2048
#define RTOT 8192      // B*T
#define DD 1024
#define HH 4
#define DKC 1024
#define DVC 2048
#define HKC 256
#define HVC 512
#define NC 32          // chunks per sequence (T/64)
#define TILE_CV 32     // conv time-tile (rows) for in-place conv

typedef unsigned short u16;
typedef unsigned int u32;
typedef short bf8v __attribute__((ext_vector_type(8)));   // 8 bf16 in 4 VGPRs
typedef float f32x4 __attribute__((ext_vector_type(4)));

__device__ __forceinline__ float bf2f(u16 u) {
    union { float f; u32 i; } c; c.i = ((u32)u) << 16; return c.f;
}
__device__ __forceinline__ u16 f2bf(float f) {
    union { float f; u32 i; } c; c.f = f;
    const u32 i = c.i;
    return (u16)((i + 0x7FFFu + ((i >> 16) & 1u)) >> 16);   // RNE; inputs finite
}
__device__ __forceinline__ float sigmoidf_(float x) { return 1.0f / (1.0f + expf(-x)); }
__device__ __forceinline__ f32x4 mfma16(bf8v a, bf8v b, f32x4 c) {
    return __builtin_amdgcn_mfma_f32_16x16x32_bf16(a, b, c, 0, 0, 0);
}

// ---------------- LayerNorm: fp32 x -> bf16 normed ----------------
__global__ __launch_bounds__(256) void ln_kernel(const float* __restrict__ x,
                                                 const float* __restrict__ w,
                                                 const float* __restrict__ b,
                                                 u16* __restrict__ out) {
    const int row = blockIdx.x;
    const int tid = threadIdx.x;
    const int lane = tid & 63, wave = tid >> 6;
    const float4 xv = *(const float4*)&x[(size_t)row * DD + tid * 4];
    float s = xv.x + xv.y + xv.z + xv.w;
    float sq = xv.x * xv.x + xv.y * xv.y + xv.z * xv.z + xv.w * xv.w;
    for (int m = 32; m >= 1; m >>= 1) {
        s += __shfl_xor(s, m, 64);
        sq += __shfl_xor(sq, m, 64);
    }
    __shared__ float s1[4], s2[4];
    if (lane == 0) { s1[wave] = s; s2[wave] = sq; }
    __syncthreads();
    const float tot = s1[0] + s1[1] + s1[2] + s1[3];
    const float totq = s2[0] + s2[1] + s2[2] + s2[3];
    const float mean = tot * (1.0f / DD);
    const float var = totq * (1.0f / DD) - mean * mean;
    const float rstd = rsqrtf(var + 1e-5f);
    const float4 wv = *(const float4*)&w[tid * 4];
    const float4 bv = *(const float4*)&b[tid * 4];
    ushort4 o;
    o.x = f2bf((xv.x - mean) * rstd * wv.x + bv.x);
    o.y = f2bf((xv.y - mean) * rstd * wv.y + bv.y);
    o.z = f2bf((xv.z - mean) * rstd * wv.z + bv.z);
    o.w = f2bf((xv.w - mean) * rstd * wv.w + bv.w);
    *(ushort4*)&out[(size_t)row * DD + tid * 4] = o;
}

// ---------------- weight transpose+convert: WT[n][k] = bf16(W[k][n]) ----------------
__global__ __launch_bounds__(256) void wconv_kernel(const float* __restrict__ W,
                                                    u16* __restrict__ WT, int K, int N) {
    __shared__ float tile[32][33];
    const int k0 = blockIdx.x * 32, n0 = blockIdx.y * 32;
    const int t = threadIdx.x;
    const int r = t >> 3, c4 = (t & 7) * 4;
    const float4 v = *(const float4*)&W[(size_t)(k0 + r) * N + n0 + c4];
    tile[r][c4 + 0] = v.x; tile[r][c4 + 1] = v.y;
    tile[r][c4 + 2] = v.z; tile[r][c4 + 3] = v.w;
    __syncthreads();
    ushort4 o;
    o.x = f2bf(tile[c4 + 0][r]); o.y = f2bf(tile[c4 + 1][r]);
    o.z = f2bf(tile[c4 + 2][r]); o.w = f2bf(tile[c4 + 3][r]);
    *(ushort4*)&WT[(size_t)(n0 + r) * K + k0 + c4] = o;
}

// ---------------- MFMA GEMM: C[M,N] = A_bf16[M,K] @ WT_bf16[N,K]^T ----------------
template <int OUTMODE>
__global__ __launch_bounds__(256, 2) void gemm_mfma(const u16* __restrict__ A,
                                                    const u16* __restrict__ BT,
                                                    void* __restrict__ Cv,
                                                    int M, int N, int K,
                                                    const float* __restrict__ Res) {
    __shared__ u16 As[128][40];
    __shared__ u16 Bs[128][40];
    const int tid = threadIdx.x;
    const int wave = tid >> 6, lane = tid & 63;
    const int quad = lane >> 4, l15 = lane & 15;
    const int wr = wave >> 1, wc = wave & 1;
    const int bn = blockIdx.x, bm = blockIdx.y;
    const int srow = tid >> 1, sh = (tid & 1) * 16;
    const u16* Ap = A + (size_t)(bm * 128 + srow) * K + sh;
    const u16* Bp = BT + (size_t)(bn * 128 + srow) * K + sh;
    f32x4 acc[4][4];
#pragma unroll
    for (int i = 0; i < 4; ++i)
#pragma unroll
        for (int j = 0; j < 4; ++j) acc[i][j] = (f32x4){0.f, 0.f, 0.f, 0.f};

    for (int k0 = 0; k0 < K; k0 += 32) {
        const bf8v a0 = *(const bf8v*)(Ap + k0);
        const bf8v a1 = *(const bf8v*)(Ap + k0 + 8);
        const bf8v b0 = *(const bf8v*)(Bp + k0);
        const bf8v b1 = *(const bf8v*)(Bp + k0 + 8);
        __syncthreads();
        *(bf8v*)&As[srow][sh] = a0;
        *(bf8v*)&As[srow][sh + 8] = a1;
        *(bf8v*)&Bs[srow][sh] = b0;
        *(bf8v*)&Bs[srow][sh + 8] = b1;
        __syncthreads();
        bf8v af[4], bfr[4];
#pragma unroll
        for (int i = 0; i < 4; ++i) af[i] = *(const bf8v*)&As[wr * 64 + i * 16 + l15][quad * 8];
#pragma unroll
        for (int j = 0; j < 4; ++j) bfr[j] = *(const bf8v*)&Bs[wc * 64 + j * 16 + l15][quad * 8];
#pragma unroll
        for (int i = 0; i < 4; ++i)
#pragma unroll
            for (int j = 0; j < 4; ++j)
                acc[i][j] = mfma16(af[i], bfr[j], acc[i][j]);
    }
#pragma unroll
    for (int i = 0; i < 4; ++i) {
        const int row = bm * 128 + wr * 64 + i * 16 + quad * 4;
#pragma unroll
        for (int j = 0; j < 4; ++j) {
            const int col = bn * 128 + wc * 64 + j * 16 + l15;
            if (OUTMODE == 0) {
                u16* C = (u16*)Cv;
#pragma unroll
                for (int r = 0; r < 4; ++r)
                    C[(size_t)(row + r) * N + col] = f2bf(acc[i][j][r]);
            } else {
                float* C = (float*)Cv;
#pragma unroll
                for (int r = 0; r < 4; ++r)
                    C[(size_t)(row + r) * N + col] = acc[i][j][r] + Res[(size_t)(row + r) * N + col];
            }
        }
    }
}

// ---------------- beta = sigmoid(n@Wb), g = -exp(A)*softplus(n@Wa+dt) ----------------
__global__ __launch_bounds__(256) void smallproj_kernel(const float* __restrict__ x,
                                                        const float* __restrict__ lnw,
                                                        const float* __restrict__ lnb,
                                                        const float* __restrict__ Wb,
                                                        const float* __restrict__ Wa,
                                                        const float* __restrict__ A_log,
                                                        const float* __restrict__ dt_bias,
                                                        float* __restrict__ beta,
                                                        float* __restrict__ gdec) {
    const int row = blockIdx.x;
    const int tid = threadIdx.x;
    const int lane = tid & 63, wave = tid >> 6;
    const float4 xv = *(const float4*)&x[(size_t)row * DD + tid * 4];
    float s = xv.x + xv.y + xv.z + xv.w;
    float sq = xv.x * xv.x + xv.y * xv.y + xv.z * xv.z + xv.w * xv.w;
    for (int m = 32; m >= 1; m >>= 1) {
        s += __shfl_xor(s, m, 64);
        sq += __shfl_xor(sq, m, 64);
    }
    __shared__ float s1[4], s2[4];
    if (lane == 0) { s1[wave] = s; s2[wave] = sq; }
    __syncthreads();
    const float mean = (s1[0] + s1[1] + s1[2] + s1[3]) * (1.0f / DD);
    const float var = (s2[0] + s2[1] + s2[2] + s2[3]) * (1.0f / DD) - mean * mean;
    const float rstd = rsqrtf(var + 1e-5f);
    const float4 wv = *(const float4*)&lnw[tid * 4];
    const float4 bv = *(const float4*)&lnb[tid * 4];
    float nv[4];
    nv[0] = (xv.x - mean) * rstd * wv.x + bv.x;
    nv[1] = (xv.y - mean) * rstd * wv.y + bv.y;
    nv[2] = (xv.z - mean) * rstd * wv.z + bv.z;
    nv[3] = (xv.w - mean) * rstd * wv.w + bv.w;
    float acc[8] = {};
#pragma unroll
    for (int j = 0; j < 4; ++j) {
        const int kk = tid * 4 + j;
        const float4 wb = ((const float4*)Wb)[kk];
        const float4 wa = ((const float4*)Wa)[kk];
        acc[0] += nv[j] * wb.x; acc[1] += nv[j] * wb.y; acc[2] += nv[j] * wb.z; acc[3] += nv[j] * wb.w;
        acc[4] += nv[j] * wa.x; acc[5] += nv[j] * wa.y; acc[6] += nv[j] * wa.z; acc[7] += nv[j] * wa.w;
    }
#pragma unroll
    for (int i = 0; i < 8; ++i)
        for (int m = 32; m >= 1; m >>= 1) acc[i] += __shfl_xor(acc[i], m, 64);
    __shared__ float sred[4][8];
    if (lane == 0)
#pragma unroll
        for (int i = 0; i < 8; ++i) sred[wave][i] = acc[i];
    __syncthreads();
    if (tid < 8) {
        const float sv = sred[0][tid] + sred[1][tid] + sred[2][tid] + sred[3][tid];
        if (tid < 4) {
            beta[(size_t)row * HH + tid] = 1.0f / (1.0f + expf(-sv));
        } else {
            const int h = tid - 4;
            const float z = sv + dt_bias[h];
            const float sp = (z > 20.0f) ? z : log1pf(expf(z));
            gdec[(size_t)row * HH + h] = -expf(A_log[h]) * sp;
        }
    }
}

// ---------------- halo save (pre-conv boundary rows per tile) ----------------
__global__ __launch_bounds__(256) void halo_save(const u16* __restrict__ P,
                                                 u16* __restrict__ halo, int C) {
    const int tt = blockIdx.x;
    const int r0 = tt * TILE_CV;
    const int t0 = r0 & (TT - 1);
    const int n4 = (3 * C) >> 2;
    for (int idx = threadIdx.x; idx < n4; idx += 256) {
        const int flat = idx * 4;
        const int j = flat / C;
        const int c = flat - j * C;
        ushort4 vv;
        if (t0 == 0) { vv.x = vv.y = vv.z = vv.w = 0; }
        else vv = *(const ushort4*)&P[(size_t)(r0 - 1 - j) * C + c];
        *(ushort4*)&halo[(size_t)(tt * 3 + j) * C + c] = vv;
    }
}

// ---------------- in-place depthwise causal conv (K=4) + SiLU, bf16 ----------------
__global__ __launch_bounds__(256) void conv_inplace(u16* __restrict__ P,
                                                    const float* __restrict__ w,
                                                    const u16* __restrict__ halo, int C) {
    const int tt = blockIdx.y;
    const int r0 = tt * TILE_CV;
    const int c0 = blockIdx.x * 1024 + threadIdx.x * 4;
    float wt[4][4];
#pragma unroll
    for (int j = 0; j < 4; ++j)
#pragma unroll
        for (int i = 0; i < 4; ++i) wt[j][i] = w[(c0 + j) * 4 + i];
    float xm1[4], xm2[4], xm3[4];
    {
        const ushort4 h0 = *(const ushort4*)&halo[(size_t)(tt * 3 + 0) * C + c0];
        const ushort4 h1 = *(const ushort4*)&halo[(size_t)(tt * 3 + 1) * C + c0];
        const ushort4 h2 = *(const ushort4*)&halo[(size_t)(tt * 3 + 2) * C + c0];
        xm1[0] = bf2f(h0.x); xm1[1] = bf2f(h0.y); xm1[2] = bf2f(h0.z); xm1[3] = bf2f(h0.w);
        xm2[0] = bf2f(h1.x); xm2[1] = bf2f(h1.y); xm2[2] = bf2f(h1.z); xm2[3] = bf2f(h1.w);
        xm3[0] = bf2f(h2.x); xm3[1] = bf2f(h2.y); xm3[2] = bf2f(h2.z); xm3[3] = bf2f(h2.w);
    }
    for (int t = 0; t < TILE_CV; ++t) {
        u16* rowp = P + (size_t)(r0 + t) * C + c0;
        const ushort4 cv = *(const ushort4*)rowp;
        float cur[4] = {bf2f(cv.x), bf2f(cv.y), bf2f(cv.z), bf2f(cv.w)};
        ushort4 ov;
        u16* op = (u16*)&ov;
#pragma unroll
        for (int j = 0; j < 4; ++j) {
            const float y = xm3[j] * wt[j][0] + xm2[j] * wt[j][1] + xm1[j] * wt[j][2] + cur[j] * wt[j][3];
            op[j] = f2bf(y * sigmoidf_(y));
        }
        *(ushort4*)rowp = ov;
#pragma unroll
        for (int j = 0; j < 4; ++j) { xm3[j] = xm2[j]; xm2[j] = xm1[j]; xm1[j] = cur[j]; }
    }
}

// ---------------- per-head l2norm for q (x 1/16) and k, in place (bf16) ----------------
__global__ __launch_bounds__(256) void normqk_kernel(u16* __restrict__ q, u16* __restrict__ k) {
    const int row = blockIdx.x;
    const int tid = threadIdx.x;
    const int h = tid >> 6, lane = tid & 63;
    const size_t base = (size_t)row * DKC + h * HKC + lane * 4;
    const ushort4 q4 = *(ushort4*)&q[base];
    const ushort4 k4 = *(ushort4*)&k[base];
    float qv[4] = {bf2f(q4.x), bf2f(q4.y), bf2f(q4.z), bf2f(q4.w)};
    float kv[4] = {bf2f(k4.x), bf2f(k4.y), bf2f(k4.z), bf2f(k4.w)};
    float sq = qv[0]*qv[0] + qv[1]*qv[1] + qv[2]*qv[2] + qv[3]*qv[3];
    float sk = kv[0]*kv[0] + kv[1]*kv[1] + kv[2]*kv[2] + kv[3]*kv[3];
    for (int m = 32; m >= 1; m >>= 1) {
        sq += __shfl_xor(sq, m, 64);
        sk += __shfl_xor(sk, m, 64);
    }
    const float qs = rsqrtf(sq + 1e-6f) * 0.0625f;
    const float ks = rsqrtf(sk + 1e-6f);
    ushort4 qo, ko;
    qo.x = f2bf(qv[0]*qs); qo.y = f2bf(qv[1]*qs); qo.z = f2bf(qv[2]*qs); qo.w = f2bf(qv[3]*qs);
    ko.x = f2bf(kv[0]*ks); ko.y = f2bf(kv[1]*ks); ko.z = f2bf(kv[2]*ks); ko.w = f2bf(kv[3]*ks);
    *(ushort4*)&q[base] = qo;
    *(ushort4*)&k[base] = ko;
}

// ---------------- P1a: per-chunk T, M=(I+T)^-1, P, gc; also kTg = k^T (MFMA transpose) ----------------
__global__ __launch_bounds__(256) void p1a_kernel(const u16* __restrict__ qg,
                                                  const u16* __restrict__ kg,
                                                  const float* __restrict__ gdec,
                                                  const float* __restrict__ beta,
                                                  u16* __restrict__ Mg,
                                                  u16* __restrict__ Pg,
                                                  u16* __restrict__ kTg,
                                                  float* __restrict__ gcg) {
    __shared__ float T[64][68];
    __shared__ float Mm[64][68];
    __shared__ float gcs[64], bars[64];
    const int CI = blockIdx.x;
    const int c = CI & 31, h = (CI >> 5) & 3, b = CI >> 7;
    const int tid = threadIdx.x, lane = tid & 63, wave = tid >> 6;
    const int quad = lane >> 4, l15 = lane & 15;
    const int rowbase = b * TT + c * 64;
    if (wave == 0) {
        float g = gdec[(size_t)(rowbase + lane) * HH + h];
        for (int d = 1; d < 64; d <<= 1) { float o2 = __shfl_up(g, d, 64); if (lane >= d) g += o2; }
        gcs[lane] = g;
        bars[lane] = beta[(size_t)(rowbase + lane) * HH + h];
        gcg[CI * 64 + lane] = g;
    }
    __syncthreads();
    const int t0 = wave * 16;
    // identity A-frags for MFMA transpose (D = I @ B = B^T)
    bf8v I0, I16;
#pragma unroll
    for (int j = 0; j < 8; ++j) {
        ((u16*)&I0)[j]  = (quad * 8 + j == l15)      ? (u16)0x3F80 : (u16)0;
        ((u16*)&I16)[j] = (quad * 8 + j == l15 + 16) ? (u16)0x3F80 : (u16)0;
    }
    f32x4 kk[4], qk[4];
#pragma unroll
    for (int st = 0; st < 4; ++st) { kk[st] = (f32x4){0,0,0,0}; qk[st] = (f32x4){0,0,0,0}; }
    const size_t arow = (size_t)(rowbase + t0 + l15) * DKC + h * HKC + quad * 8;
    for (int ks = 0; ks < 8; ++ks) {
        const bf8v ak = *(const bf8v*)(kg + arow + ks * 32);
        const bf8v aq = *(const bf8v*)(qg + arow + ks * 32);
        // transpose this k block: D[m][n] = ak[n][m(+16)]
        f32x4 tr0 = (f32x4){0,0,0,0}, tr1 = (f32x4){0,0,0,0};
        tr0 = mfma16(I0, ak, tr0);
        tr1 = mfma16(I16, ak, tr1);
        const size_t kbase = (size_t)CI * 16384 + t0 + l15;
#pragma unroll
        for (int i = 0; i < 4; ++i) {
            kTg[kbase + (size_t)(ks * 32 + quad * 4 + i) * 64] = f2bf(tr0[i]);
            kTg[kbase + (size_t)(ks * 32 + 16 + quad * 4 + i) * 64] = f2bf(tr1[i]);
        }
#pragma unroll
        for (int st = 0; st < 4; ++st) {
            const size_t brow = (size_t)(rowbase + st * 16 + l15) * DKC + h * HKC + quad * 8 + ks * 32;
            const bf8v bk = *(const bf8v*)(kg + brow);
            kk[st] = mfma16(ak, bk, kk[st]);
            qk[st] = mfma16(aq, bk, qk[st]);
        }
    }
#pragma unroll
    for (int st = 0; st < 4; ++st)
#pragma unroll
        for (int i = 0; i < 4; ++i) {
            const int t = t0 + quad * 4 + i, s = st * 16 + l15;
            const float e = expf(gcs[t] - gcs[s]);
            T[t][s] = (s < t) ? bars[t] * e * kk[st][i] : 0.f;
            Pg[(size_t)CI * 4096 + t * 64 + s] = f2bf((s <= t) ? e * qk[st][i] : 0.f);
        }
    __syncthreads();
    if (wave == 0) {
        const int j = lane;
        Mm[0][j] = (j == 0) ? 1.f : 0.f;
        for (int t = 1; t < 64; ++t) {
            float acc = 0.f;
            for (int s = 0; s < t; ++s) acc += T[t][s] * Mm[s][j];
            Mm[t][j] = ((t == j) ? 1.f : 0.f) - acc;
        }
    }
    __syncthreads();
    for (int idx = tid; idx < 4096; idx += 256)
        Mg[(size_t)CI * 4096 + idx] = f2bf(Mm[idx >> 6][idx & 63]);
}

// ---------------- P2: inter-chunk recurrence. A-operands direct from global; 3 barriers/chunk ----------------
// grid = B*H*(HVC/32) = 256 blocks, 512 threads (8 waves: tw = wave>>1 t-tile, nw = wave&1 n-half).
// State S[256][32] fp32 in regs (4 tiles/wave); bf16 shadow S^T double-buffered in LDS.
__global__ __launch_bounds__(512) void p2_kernel(const u16* __restrict__ qg,
                                                 const u16* __restrict__ kg,
                                                 const u16* __restrict__ vg,
                                                 const float* __restrict__ beta,
                                                 const float* __restrict__ gcg,
                                                 const u16* __restrict__ Mg,
                                                 const u16* __restrict__ Pg,
                                                 const u16* __restrict__ kTg,
                                                 u16* __restrict__ og) {
    __shared__ u16 SbT[2][32][264];   // S^T shadow [n][r], dbuf
    __shared__ u16 uT[32][72];        // u^T  [n][s]
    __shared__ u16 vT[32][72];        // veff^T [n][s]
    __shared__ u16 v2T[32][72];       // (gcdg*veff)^T [n][s]
    const int bid = blockIdx.x;
    const int vs = bid & 15, h = (bid >> 4) & 3, b = bid >> 6;
    const int tid = threadIdx.x, lane = tid & 63, wave = tid >> 6;
    const int quad = lane >> 4, l15 = lane & 15;
    const int tw = wave >> 1, nw = wave & 1;
    const int t0 = tw * 16;
    const int ncol = nw * 16 + l15;                 // n within the 32-col slice
    for (int i = tid; i < 32 * 264; i += 512) ((u16*)SbT[0])[i] = 0;
    f32x4 S[4];
#pragma unroll
    for (int a = 0; a < 4; ++a) S[a] = (f32x4){0,0,0,0};
    __syncthreads();

    for (int c = 0; c < NC; ++c) {
        const int cur = c & 1, nxt = cur ^ 1;
        const int CI = (b * 4 + h) * NC + c;
        const int rowbase = b * TT + c * 64;
        // per-lane row scalars for rows t = t0 + quad*4 + i
        const float gc63 = gcg[CI * 64 + 63];
        float bt[4], ga[4], gd[4];
#pragma unroll
        for (int i = 0; i < 4; ++i) {
            const int t = t0 + quad * 4 + i;
            bt[i] = beta[(size_t)(rowbase + t) * HH + h];
            const float gc = gcg[CI * 64 + t];
            ga[i] = expf(gc);            // gamma_t
            gd[i] = expf(gc63 - gc);     // gamma_C / gamma_t
        }
        const size_t krow = (size_t)(rowbase + t0 + l15) * DKC + h * HKC + quad * 8;
        // ---- phase1: ksacc = k @ S ; u = bt*v - bt*ga*ksacc ; write uT ----
        f32x4 ka0 = (f32x4){0,0,0,0}, ka1 = (f32x4){0,0,0,0};
        for (int ks = 0; ks < 8; ks += 2) {
            const bf8v ak0 = *(const bf8v*)(kg + krow + ks * 32);
            const bf8v ak1 = *(const bf8v*)(kg + krow + ks * 32 + 32);
            const bf8v bs0 = *(const bf8v*)(&SbT[cur][ncol][ks * 32 + quad * 8]);
            const bf8v bs1 = *(const bf8v*)(&SbT[cur][ncol][ks * 32 + 32 + quad * 8]);
            ka0 = mfma16(ak0, bs0, ka0);
            ka1 = mfma16(ak1, bs1, ka1);
        }
        {
            ushort4 up; u16* upp = (u16*)&up;
#pragma unroll
            for (int i = 0; i < 4; ++i) {
                const int t = t0 + quad * 4 + i;
                const float vv = bf2f(vg[(size_t)(rowbase + t) * DVC + h * HVC + vs * 32 + ncol]);
                upp[i] = f2bf(bt[i] * vv - bt[i] * ga[i] * (ka0[i] + ka1[i]));
            }
            *(ushort4*)(&uT[ncol][t0 + quad * 4]) = up;
        }
        __syncthreads();
        // ---- phase2: veff = M @ u ; write vT (raw), v2T (gd-scaled) ----
        f32x4 vacc = (f32x4){0,0,0,0};
        for (int ks = 0; ks < 2; ++ks) {
            const bf8v am = *(const bf8v*)(Mg + (size_t)CI * 4096 + (t0 + l15) * 64 + ks * 32 + quad * 8);
            const bf8v bu = *(const bf8v*)(&uT[ncol][ks * 32 + quad * 8]);
            vacc = mfma16(am, bu, vacc);
        }
        {
            ushort4 vp, v2p; u16* vpp = (u16*)&vp; u16* v2pp = (u16*)&v2p;
#pragma unroll
            for (int i = 0; i < 4; ++i) {
                vpp[i] = f2bf(vacc[i]);
                v2pp[i] = f2bf(vacc[i] * gd[i]);
            }
            *(ushort4*)(&vT[ncol][t0 + quad * 4]) = vp;
            *(ushort4*)(&v2T[ncol][t0 + quad * 4]) = v2p;
        }
        __syncthreads();
        // ---- phase3: o = P@veff + ga * (q@S) ----
        f32x4 op_ = (f32x4){0,0,0,0};
        for (int ks = 0; ks < 2; ++ks) {
            const bf8v ap = *(const bf8v*)(Pg + (size_t)CI * 4096 + (t0 + l15) * 64 + ks * 32 + quad * 8);
            const bf8v bv_ = *(const bf8v*)(&vT[ncol][ks * 32 + quad * 8]);
            op_ = mfma16(ap, bv_, op_);
        }
        f32x4 oq0 = (f32x4){0,0,0,0}, oq1 = (f32x4){0,0,0,0};
        const size_t qrow = (size_t)(rowbase + t0 + l15) * DKC + h * HKC + quad * 8;
        for (int ks = 0; ks < 8; ks += 2) {
            const bf8v aq0 = *(const bf8v*)(qg + qrow + ks * 32);
            const bf8v aq1 = *(const bf8v*)(qg + qrow + ks * 32 + 32);
            const bf8v bs0 = *(const bf8v*)(&SbT[cur][ncol][ks * 32 + quad * 8]);
            const bf8v bs1 = *(const bf8v*)(&SbT[cur][ncol][ks * 32 + 32 + quad * 8]);
            oq0 = mfma16(aq0, bs0, oq0);
            oq1 = mfma16(aq1, bs1, oq1);
        }
#pragma unroll
        for (int i = 0; i < 4; ++i) {
            const int t = t0 + quad * 4 + i;
            og[((size_t)(b * 4 + h) * TT + c * 64 + t) * HVC + vs * 32 + ncol] =
                f2bf(op_[i] + ga[i] * (oq0[i] + oq1[i]));
        }
        // ---- phase4 (same region, SbT dbuf): S = gC*S + kT @ v2 ; write SbT[nxt] ----
        const float gC = expf(gc63);
#pragma unroll
        for (int a = 0; a < 4; ++a) {
            const int r0 = (tw * 4 + a) * 16;
            f32x4 acc = S[a] * gC;
            for (int ks = 0; ks < 2; ++ks) {
                const bf8v akt = *(const bf8v*)(kTg + (size_t)CI * 16384 + (r0 + l15) * 64 + ks * 32 + quad * 8);
                const bf8v bv2 = *(const bf8v*)(&v2T[ncol][ks * 32 + quad * 8]);
                acc = mfma16(akt, bv2, acc);
            }
            S[a] = acc;
            ushort4 sp; u16* spp = (u16*)&sp;
#pragma unroll
            for (int i = 0; i < 4; ++i) spp[i] = f2bf(acc[i]);
            *(ushort4*)(&SbT[nxt][ncol][r0 + quad * 4]) = sp;
        }
        __syncthreads();
    }
}

// ---------------- RMSNorm + silu-gate; reads o (chunk layout), writes pg in place ----------------
__global__ __launch_bounds__(256) void gate_kernel(const u16* __restrict__ o,
                                                   u16* __restrict__ pg,
                                                   const float* __restrict__ norm_w) {
    const int row = blockIdx.x;
    const int b = row >> 11, t = row & 2047;
    const int tid = threadIdx.x;
    const int h = tid >> 6, lane = tid & 63;
    const size_t obase = ((size_t)(b * 4 + h) * TT + t) * HVC + lane * 4;
    const size_t pbase = (size_t)row * DVC + h * HVC + lane * 4;
    const ushort4 a4 = *(const ushort4*)&o[obase];
    const ushort4 b4 = *(const ushort4*)&o[obase + 256];
    float o1[4] = {bf2f(a4.x), bf2f(a4.y), bf2f(a4.z), bf2f(a4.w)};
    float o2[4] = {bf2f(b4.x), bf2f(b4.y), bf2f(b4.z), bf2f(b4.w)};
    float ss = 0.f;
#pragma unroll
    for (int j = 0; j < 4; ++j) ss += o1[j]*o1[j] + o2[j]*o2[j];
    for (int m = 32; m >= 1; m >>= 1) ss += __shfl_xor(ss, m, 64);
    const float rms = rsqrtf(ss * (1.0f / HVC) + 1e-5f);
    const float4 nw1 = *(const float4*)&norm_w[lane * 4];
    const float4 nw2 = *(const float4*)&norm_w[256 + lane * 4];
    const ushort4 g4a = *(const ushort4*)&pg[pbase];
    const ushort4 g4b = *(const ushort4*)&pg[pbase + 256];
    const float g1[4] = {bf2f(g4a.x), bf2f(g4a.y), bf2f(g4a.z), bf2f(g4a.w)};
    const float g2[4] = {bf2f(g4b.x), bf2f(g4b.y), bf2f(g4b.z), bf2f(g4b.w)};
    const float n1[4] = {nw1.x, nw1.y, nw1.z, nw1.w};
    const float n2[4] = {nw2.x, nw2.y, nw2.z, nw2.w};
    ushort4 r1, r2;
    u16* p1 = (u16*)&r1; u16* p2 = (u16*)&r2;
#pragma unroll
    for (int j = 0; j < 4; ++j) {
        p1[j] = f2bf(o1[j] * rms * n1[j] * g1[j] * sigmoidf_(g1[j]));
        p2[j] = f2bf(o2[j] * rms * n2[j] * g2[j] * sigmoidf_(g2[j]));
    }
    *(ushort4*)&pg[pbase] = r1;
    *(ushort4*)&pg[pbase + 256] = r2;
}

extern "C" void kernel_launch(void* const* d_in, const int* in_sizes, int n_in,
                              void* d_out, int out_size, void* d_ws, size_t ws_size,
                              hipStream_t stream) {
    const float* x       = (const float*)d_in[0];
    const float* ln_w    = (const float*)d_in[1];
    const float* ln_b    = (const float*)d_in[2];
    const float* Wq      = (const float*)d_in[3];
    const float* Wk      = (const float*)d_in[4];
    const float* Wv      = (const float*)d_in[5];
    const float* conv_q  = (const float*)d_in[6];
    const float* conv_k  = (const float*)d_in[7];
    const float* conv_v  = (const float*)d_in[8];
    const float* Wb      = (const float*)d_in[9];
    const float* Wa      = (const float*)d_in[10];
    const float* A_log   = (const float*)d_in[11];
    const float* dt_bias = (const float*)d_in[12];
    const float* Wg      = (const float*)d_in[13];
    const float* norm_w  = (const float*)d_in[14];
    const float* Wo      = (const float*)d_in[15];
    float* out = (float*)d_out;

    // Workspace layout: 124 MB peak (unchanged); kTg (16MB) lives in d_out (dead until final GEMM)
    char* ws = (char*)d_ws;
    u16* normed = (u16*)(ws);                           // 16MB [0,16)
    u16* q      = (u16*)(ws + (16ull << 20));           // 16MB [16,32)
    u16* k      = (u16*)(ws + (32ull << 20));           // 16MB [32,48)
    u16* v      = (u16*)(ws + (48ull << 20));           // 32MB [48,80)
    u16* o      = (u16*)(ws + (80ull << 20));           // 32MB [80,112) chunk layout [B,H,T,HV]
    float* beta = (float*)(ws + (112ull << 20));              // 128KB
    float* gdec = (float*)(ws + (112ull << 20) + (128u<<10)); // 128KB
    float* gcg  = (float*)(ws + (112ull << 20) + (256u<<10)); // 128KB
    u16* halo   = (u16*)(ws + (113ull << 20));          // 3MB
    u16* Mg     = (u16*)(ws + (116ull << 20));          // 4MB
    u16* Pg     = (u16*)(ws + (120ull << 20));          // 4MB
    u16* pg     = q;                                    // 32MB (q+k region) after p2
    u16* WTe    = o;                                    // early weight-T scratch (o free until p2)
    u16* WgT    = Mg;                                   // Mg free after p2
    u16* WoT    = v;                                    // v free after p2
    u16* kTg    = (u16*)d_out;                          // 16MB k^T chunks; overwritten by final GEMM

    ln_kernel<<<RTOT, 256, 0, stream>>>(x, ln_w, ln_b, normed);

    wconv_kernel<<<dim3(DD / 32, DKC / 32), 256, 0, stream>>>(Wq, WTe, DD, DKC);
    gemm_mfma<0><<<dim3(DKC / 128, RTOT / 128), 256, 0, stream>>>(normed, WTe, q, RTOT, DKC, DD, nullptr);
    wconv_kernel<<<dim3(DD / 32, DKC / 32), 256, 0, stream>>>(Wk, WTe, DD, DKC);
    gemm_mfma<0><<<dim3(DKC / 128, RTOT / 128), 256, 0, stream>>>(normed, WTe, k, RTOT, DKC, DD, nullptr);
    wconv_kernel<<<dim3(DD / 32, DVC / 32), 256, 0, stream>>>(Wv, WTe, DD, DVC);
    gemm_mfma<0><<<dim3(DVC / 128, RTOT / 128), 256, 0, stream>>>(normed, WTe, v, RTOT, DVC, DD, nullptr);
    smallproj_kernel<<<RTOT, 256, 0, stream>>>(x, ln_w, ln_b, Wb, Wa, A_log, dt_bias, beta, gdec);

    halo_save<<<RTOT / TILE_CV, 256, 0, stream>>>(q, halo, DKC);
    conv_inplace<<<dim3(1, RTOT / TILE_CV), 256, 0, stream>>>(q, conv_q, halo, DKC);
    halo_save<<<RTOT / TILE_CV, 256, 0, stream>>>(k, halo, DKC);
    conv_inplace<<<dim3(1, RTOT / TILE_CV), 256, 0, stream>>>(k, conv_k, halo, DKC);
    halo_save<<<RTOT / TILE_CV, 256, 0, stream>>>(v, halo, DVC);
    conv_inplace<<<dim3(2, RTOT / TILE_CV), 256, 0, stream>>>(v, conv_v, halo, DVC);

    normqk_kernel<<<RTOT, 256, 0, stream>>>(q, k);

    p1a_kernel<<<BB * HH * NC, 256, 0, stream>>>(q, k, gdec, beta, Mg, Pg, kTg, gcg);
    p2_kernel<<<BB * HH * (HVC / 32), 512, 0, stream>>>(q, k, v, beta, gcg, Mg, Pg, kTg, o);

    // q,k dead -> pg; Mg dead -> WgT; v dead -> WoT
    wconv_kernel<<<dim3(DD / 32, DVC / 32), 256, 0, stream>>>(Wg, WgT, DD, DVC);
    gemm_mfma<0><<<dim3(DVC / 128, RTOT / 128), 256, 0, stream>>>(normed, WgT, pg, RTOT, DVC, DD, nullptr);

    gate_kernel<<<RTOT, 256, 0, stream>>>(o, pg, norm_w);

    wconv_kernel<<<dim3(DVC / 32, DD / 32), 256, 0, stream>>>(Wo, WoT, DVC, DD);
    gemm_mfma<1><<<dim3(DD / 128, RTOT / 128), 256, 0, stream>>>(pg, WoT, out, RTOT, DD, DVC, x);
}

// Round 8
// 756.833 us; speedup vs baseline: 1.0479x; 1.0479x over previous
//
#include <hip/hip_runtime.h>
#include <math.h>

// Problem constants (match reference)
#define BB 4
#define TT 2048
#define RTOT 8192      // B*T
#define DD 1024
#define HH 4
#define DKC 1024
#define DVC 2048
#define HKC 256
#define HVC 512
#define NC 32          // chunks per sequence (T/64)
#define TILE_CV 32     // conv time-tile (rows) for in-place conv

typedef unsigned short u16;
typedef unsigned int u32;
typedef short bf8v __attribute__((ext_vector_type(8)));   // 8 bf16 in 4 VGPRs
typedef float f32x4 __attribute__((ext_vector_type(4)));

__device__ __forceinline__ float bf2f(u16 u) {
    union { float f; u32 i; } c; c.i = ((u32)u) << 16; return c.f;
}
__device__ __forceinline__ u16 f2bf(float f) {
    union { float f; u32 i; } c; c.f = f;
    const u32 i = c.i;
    return (u16)((i + 0x7FFFu + ((i >> 16) & 1u)) >> 16);   // RNE; inputs finite
}
__device__ __forceinline__ float sigmoidf_(float x) { return 1.0f / (1.0f + expf(-x)); }
__device__ __forceinline__ f32x4 mfma16(bf8v a, bf8v b, f32x4 c) {
    return __builtin_amdgcn_mfma_f32_16x16x32_bf16(a, b, c, 0, 0, 0);
}

// ---------------- LayerNorm: fp32 x -> bf16 normed ----------------
__global__ __launch_bounds__(256) void ln_kernel(const float* __restrict__ x,
                                                 const float* __restrict__ w,
                                                 const float* __restrict__ b,
                                                 u16* __restrict__ out) {
    const int row = blockIdx.x;
    const int tid = threadIdx.x;
    const int lane = tid & 63, wave = tid >> 6;
    const float4 xv = *(const float4*)&x[(size_t)row * DD + tid * 4];
    float s = xv.x + xv.y + xv.z + xv.w;
    float sq = xv.x * xv.x + xv.y * xv.y + xv.z * xv.z + xv.w * xv.w;
    for (int m = 32; m >= 1; m >>= 1) {
        s += __shfl_xor(s, m, 64);
        sq += __shfl_xor(sq, m, 64);
    }
    __shared__ float s1[4], s2[4];
    if (lane == 0) { s1[wave] = s; s2[wave] = sq; }
    __syncthreads();
    const float tot = s1[0] + s1[1] + s1[2] + s1[3];
    const float totq = s2[0] + s2[1] + s2[2] + s2[3];
    const float mean = tot * (1.0f / DD);
    const float var = totq * (1.0f / DD) - mean * mean;
    const float rstd = rsqrtf(var + 1e-5f);
    const float4 wv = *(const float4*)&w[tid * 4];
    const float4 bv = *(const float4*)&b[tid * 4];
    ushort4 o;
    o.x = f2bf((xv.x - mean) * rstd * wv.x + bv.x);
    o.y = f2bf((xv.y - mean) * rstd * wv.y + bv.y);
    o.z = f2bf((xv.z - mean) * rstd * wv.z + bv.z);
    o.w = f2bf((xv.w - mean) * rstd * wv.w + bv.w);
    *(ushort4*)&out[(size_t)row * DD + tid * 4] = o;
}

// ---------------- weight transpose+convert: WT[n][k] = bf16(W[k][n]) ----------------
__global__ __launch_bounds__(256) void wconv_kernel(const float* __restrict__ W,
                                                    u16* __restrict__ WT, int K, int N) {
    __shared__ float tile[32][33];
    const int k0 = blockIdx.x * 32, n0 = blockIdx.y * 32;
    const int t = threadIdx.x;
    const int r = t >> 3, c4 = (t & 7) * 4;
    const float4 v = *(const float4*)&W[(size_t)(k0 + r) * N + n0 + c4];
    tile[r][c4 + 0] = v.x; tile[r][c4 + 1] = v.y;
    tile[r][c4 + 2] = v.z; tile[r][c4 + 3] = v.w;
    __syncthreads();
    ushort4 o;
    o.x = f2bf(tile[c4 + 0][r]); o.y = f2bf(tile[c4 + 1][r]);
    o.z = f2bf(tile[c4 + 2][r]); o.w = f2bf(tile[c4 + 3][r]);
    *(ushort4*)&WT[(size_t)(n0 + r) * K + k0 + c4] = o;
}

// ---------------- MFMA GEMM: C[M,N] = A_bf16[M,K] @ WT_bf16[N,K]^T ----------------
// 128x128 tile, BK=32, 4 waves (2x2). Round-5 proven staging (vector load + ds_write,
// padded stride 40) — global_load_lds variant suspected in container deaths r6/r7.
template <int OUTMODE>
__global__ __launch_bounds__(256, 2) void gemm_mfma(const u16* __restrict__ A,
                                                    const u16* __restrict__ BT,
                                                    void* __restrict__ Cv,
                                                    int M, int N, int K,
                                                    const float* __restrict__ Res) {
    __shared__ u16 As[128][40];   // stride 40 bf16 = 80B (16B-aligned rows)
    __shared__ u16 Bs[128][40];
    const int tid = threadIdx.x;
    const int wave = tid >> 6, lane = tid & 63;
    const int quad = lane >> 4, l15 = lane & 15;
    const int wr = wave >> 1, wc = wave & 1;
    const int bn = blockIdx.x, bm = blockIdx.y;
    const int srow = tid >> 1, sh = (tid & 1) * 16;
    const u16* Ap = A + (size_t)(bm * 128 + srow) * K + sh;
    const u16* Bp = BT + (size_t)(bn * 128 + srow) * K + sh;
    f32x4 acc[4][4];
#pragma unroll
    for (int i = 0; i < 4; ++i)
#pragma unroll
        for (int j = 0; j < 4; ++j) acc[i][j] = (f32x4){0.f, 0.f, 0.f, 0.f};

    for (int k0 = 0; k0 < K; k0 += 32) {
        const bf8v a0 = *(const bf8v*)(Ap + k0);
        const bf8v a1 = *(const bf8v*)(Ap + k0 + 8);
        const bf8v b0 = *(const bf8v*)(Bp + k0);
        const bf8v b1 = *(const bf8v*)(Bp + k0 + 8);
        __syncthreads();                       // prev-iter LDS reads done
        *(bf8v*)&As[srow][sh] = a0;
        *(bf8v*)&As[srow][sh + 8] = a1;
        *(bf8v*)&Bs[srow][sh] = b0;
        *(bf8v*)&Bs[srow][sh + 8] = b1;
        __syncthreads();                       // staged
        bf8v af[4], bfr[4];
#pragma unroll
        for (int i = 0; i < 4; ++i) af[i] = *(const bf8v*)&As[wr * 64 + i * 16 + l15][quad * 8];
#pragma unroll
        for (int j = 0; j < 4; ++j) bfr[j] = *(const bf8v*)&Bs[wc * 64 + j * 16 + l15][quad * 8];
#pragma unroll
        for (int i = 0; i < 4; ++i)
#pragma unroll
            for (int j = 0; j < 4; ++j)
                acc[i][j] = mfma16(af[i], bfr[j], acc[i][j]);
    }
#pragma unroll
    for (int i = 0; i < 4; ++i) {
        const int row = bm * 128 + wr * 64 + i * 16 + quad * 4;
#pragma unroll
        for (int j = 0; j < 4; ++j) {
            const int col = bn * 128 + wc * 64 + j * 16 + l15;
            if (OUTMODE == 0) {
                u16* C = (u16*)Cv;
#pragma unroll
                for (int r = 0; r < 4; ++r)
                    C[(size_t)(row + r) * N + col] = f2bf(acc[i][j][r]);
            } else {
                float* C = (float*)Cv;
#pragma unroll
                for (int r = 0; r < 4; ++r)
                    C[(size_t)(row + r) * N + col] = acc[i][j][r] + Res[(size_t)(row + r) * N + col];
            }
        }
    }
}

// ---------------- beta = sigmoid(n@Wb), g = -exp(A)*softplus(n@Wa+dt) ----------------
__global__ __launch_bounds__(256) void smallproj_kernel(const float* __restrict__ x,
                                                        const float* __restrict__ lnw,
                                                        const float* __restrict__ lnb,
                                                        const float* __restrict__ Wb,
                                                        const float* __restrict__ Wa,
                                                        const float* __restrict__ A_log,
                                                        const float* __restrict__ dt_bias,
                                                        float* __restrict__ beta,
                                                        float* __restrict__ gdec) {
    const int row = blockIdx.x;
    const int tid = threadIdx.x;
    const int lane = tid & 63, wave = tid >> 6;
    const float4 xv = *(const float4*)&x[(size_t)row * DD + tid * 4];
    float s = xv.x + xv.y + xv.z + xv.w;
    float sq = xv.x * xv.x + xv.y * xv.y + xv.z * xv.z + xv.w * xv.w;
    for (int m = 32; m >= 1; m >>= 1) {
        s += __shfl_xor(s, m, 64);
        sq += __shfl_xor(sq, m, 64);
    }
    __shared__ float s1[4], s2[4];
    if (lane == 0) { s1[wave] = s; s2[wave] = sq; }
    __syncthreads();
    const float mean = (s1[0] + s1[1] + s1[2] + s1[3]) * (1.0f / DD);
    const float var = (s2[0] + s2[1] + s2[2] + s2[3]) * (1.0f / DD) - mean * mean;
    const float rstd = rsqrtf(var + 1e-5f);
    const float4 wv = *(const float4*)&lnw[tid * 4];
    const float4 bv = *(const float4*)&lnb[tid * 4];
    float nv[4];
    nv[0] = (xv.x - mean) * rstd * wv.x + bv.x;
    nv[1] = (xv.y - mean) * rstd * wv.y + bv.y;
    nv[2] = (xv.z - mean) * rstd * wv.z + bv.z;
    nv[3] = (xv.w - mean) * rstd * wv.w + bv.w;
    float acc[8] = {};
#pragma unroll
    for (int j = 0; j < 4; ++j) {
        const int kk = tid * 4 + j;
        const float4 wb = ((const float4*)Wb)[kk];
        const float4 wa = ((const float4*)Wa)[kk];
        acc[0] += nv[j] * wb.x; acc[1] += nv[j] * wb.y; acc[2] += nv[j] * wb.z; acc[3] += nv[j] * wb.w;
        acc[4] += nv[j] * wa.x; acc[5] += nv[j] * wa.y; acc[6] += nv[j] * wa.z; acc[7] += nv[j] * wa.w;
    }
#pragma unroll
    for (int i = 0; i < 8; ++i)
        for (int m = 32; m >= 1; m >>= 1) acc[i] += __shfl_xor(acc[i], m, 64);
    __shared__ float sred[4][8];
    if (lane == 0)
#pragma unroll
        for (int i = 0; i < 8; ++i) sred[wave][i] = acc[i];
    __syncthreads();
    if (tid < 8) {
        const float sv = sred[0][tid] + sred[1][tid] + sred[2][tid] + sred[3][tid];
        if (tid < 4) {
            beta[(size_t)row * HH + tid] = 1.0f / (1.0f + expf(-sv));
        } else {
            const int h = tid - 4;
            const float z = sv + dt_bias[h];
            const float sp = (z > 20.0f) ? z : log1pf(expf(z));
            gdec[(size_t)row * HH + h] = -expf(A_log[h]) * sp;
        }
    }
}

// ---------------- halo save (pre-conv boundary rows per tile) ----------------
__global__ __launch_bounds__(256) void halo_save(const u16* __restrict__ P,
                                                 u16* __restrict__ halo, int C) {
    const int tt = blockIdx.x;
    const int r0 = tt * TILE_CV;
    const int t0 = r0 & (TT - 1);
    const int n4 = (3 * C) >> 2;
    for (int idx = threadIdx.x; idx < n4; idx += 256) {
        const int flat = idx * 4;
        const int j = flat / C;
        const int c = flat - j * C;
        ushort4 vv;
        if (t0 == 0) { vv.x = vv.y = vv.z = vv.w = 0; }
        else vv = *(const ushort4*)&P[(size_t)(r0 - 1 - j) * C + c];
        *(ushort4*)&halo[(size_t)(tt * 3 + j) * C + c] = vv;
    }
}

// ---------------- in-place depthwise causal conv (K=4) + SiLU, bf16 ----------------
__global__ __launch_bounds__(256) void conv_inplace(u16* __restrict__ P,
                                                    const float* __restrict__ w,
                                                    const u16* __restrict__ halo, int C) {
    const int tt = blockIdx.y;
    const int r0 = tt * TILE_CV;
    const int c0 = blockIdx.x * 1024 + threadIdx.x * 4;
    float wt[4][4];
#pragma unroll
    for (int j = 0; j < 4; ++j)
#pragma unroll
        for (int i = 0; i < 4; ++i) wt[j][i] = w[(c0 + j) * 4 + i];
    float xm1[4], xm2[4], xm3[4];
    {
        const ushort4 h0 = *(const ushort4*)&halo[(size_t)(tt * 3 + 0) * C + c0];
        const ushort4 h1 = *(const ushort4*)&halo[(size_t)(tt * 3 + 1) * C + c0];
        const ushort4 h2 = *(const ushort4*)&halo[(size_t)(tt * 3 + 2) * C + c0];
        xm1[0] = bf2f(h0.x); xm1[1] = bf2f(h0.y); xm1[2] = bf2f(h0.z); xm1[3] = bf2f(h0.w);
        xm2[0] = bf2f(h1.x); xm2[1] = bf2f(h1.y); xm2[2] = bf2f(h1.z); xm2[3] = bf2f(h1.w);
        xm3[0] = bf2f(h2.x); xm3[1] = bf2f(h2.y); xm3[2] = bf2f(h2.z); xm3[3] = bf2f(h2.w);
    }
    for (int t = 0; t < TILE_CV; ++t) {
        u16* rowp = P + (size_t)(r0 + t) * C + c0;
        const ushort4 cv = *(const ushort4*)rowp;
        float cur[4] = {bf2f(cv.x), bf2f(cv.y), bf2f(cv.z), bf2f(cv.w)};
        ushort4 ov;
        u16* op = (u16*)&ov;
#pragma unroll
        for (int j = 0; j < 4; ++j) {
            const float y = xm3[j] * wt[j][0] + xm2[j] * wt[j][1] + xm1[j] * wt[j][2] + cur[j] * wt[j][3];
            op[j] = f2bf(y * sigmoidf_(y));
        }
        *(ushort4*)rowp = ov;
#pragma unroll
        for (int j = 0; j < 4; ++j) { xm3[j] = xm2[j]; xm2[j] = xm1[j]; xm1[j] = cur[j]; }
    }
}

// ---------------- per-head l2norm for q (x 1/16) and k, in place (bf16) ----------------
__global__ __launch_bounds__(256) void normqk_kernel(u16* __restrict__ q, u16* __restrict__ k) {
    const int row = blockIdx.x;
    const int tid = threadIdx.x;
    const int h = tid >> 6, lane = tid & 63;
    const size_t base = (size_t)row * DKC + h * HKC + lane * 4;
    const ushort4 q4 = *(ushort4*)&q[base];
    const ushort4 k4 = *(ushort4*)&k[base];
    float qv[4] = {bf2f(q4.x), bf2f(q4.y), bf2f(q4.z), bf2f(q4.w)};
    float kv[4] = {bf2f(k4.x), bf2f(k4.y), bf2f(k4.z), bf2f(k4.w)};
    float sq = qv[0]*qv[0] + qv[1]*qv[1] + qv[2]*qv[2] + qv[3]*qv[3];
    float sk = kv[0]*kv[0] + kv[1]*kv[1] + kv[2]*kv[2] + kv[3]*kv[3];
    for (int m = 32; m >= 1; m >>= 1) {
        sq += __shfl_xor(sq, m, 64);
        sk += __shfl_xor(sk, m, 64);
    }
    const float qs = rsqrtf(sq + 1e-6f) * 0.0625f;
    const float ks = rsqrtf(sk + 1e-6f);
    ushort4 qo, ko;
    qo.x = f2bf(qv[0]*qs); qo.y = f2bf(qv[1]*qs); qo.z = f2bf(qv[2]*qs); qo.w = f2bf(qv[3]*qs);
    ko.x = f2bf(kv[0]*ks); ko.y = f2bf(kv[1]*ks); ko.z = f2bf(kv[2]*ks); ko.w = f2bf(kv[3]*ks);
    *(ushort4*)&q[base] = qo;
    *(ushort4*)&k[base] = ko;
}

// ---------------- P1a: per-chunk T, M=(I+T)^-1, P, gc; also kTg = k^T (MFMA transpose) ----------------
__global__ __launch_bounds__(256) void p1a_kernel(const u16* __restrict__ qg,
                                                  const u16* __restrict__ kg,
                                                  const float* __restrict__ gdec,
                                                  const float* __restrict__ beta,
                                                  u16* __restrict__ Mg,
                                                  u16* __restrict__ Pg,
                                                  u16* __restrict__ kTg,
                                                  float* __restrict__ gcg) {
    __shared__ float T[64][68];
    __shared__ float Mm[64][68];
    __shared__ float gcs[64], bars[64];
    const int CI = blockIdx.x;
    const int c = CI & 31, h = (CI >> 5) & 3, b = CI >> 7;
    const int tid = threadIdx.x, lane = tid & 63, wave = tid >> 6;
    const int quad = lane >> 4, l15 = lane & 15;
    const int rowbase = b * TT + c * 64;
    if (wave == 0) {
        float g = gdec[(size_t)(rowbase + lane) * HH + h];
        for (int d = 1; d < 64; d <<= 1) { float o2 = __shfl_up(g, d, 64); if (lane >= d) g += o2; }
        gcs[lane] = g;
        bars[lane] = beta[(size_t)(rowbase + lane) * HH + h];
        gcg[CI * 64 + lane] = g;
    }
    __syncthreads();
    const int t0 = wave * 16;
    bf8v I0, I16;
#pragma unroll
    for (int j = 0; j < 8; ++j) {
        ((u16*)&I0)[j]  = (quad * 8 + j == l15)      ? (u16)0x3F80 : (u16)0;
        ((u16*)&I16)[j] = (quad * 8 + j == l15 + 16) ? (u16)0x3F80 : (u16)0;
    }
    f32x4 kk[4], qk[4];
#pragma unroll
    for (int st = 0; st < 4; ++st) { kk[st] = (f32x4){0,0,0,0}; qk[st] = (f32x4){0,0,0,0}; }
    const size_t arow = (size_t)(rowbase + t0 + l15) * DKC + h * HKC + quad * 8;
    for (int ks = 0; ks < 8; ++ks) {
        const bf8v ak = *(const bf8v*)(kg + arow + ks * 32);
        const bf8v aq = *(const bf8v*)(qg + arow + ks * 32);
        f32x4 tr0 = (f32x4){0,0,0,0}, tr1 = (f32x4){0,0,0,0};
        tr0 = mfma16(I0, ak, tr0);
        tr1 = mfma16(I16, ak, tr1);
        const size_t kbase = (size_t)CI * 16384 + t0 + l15;
#pragma unroll
        for (int i = 0; i < 4; ++i) {
            kTg[kbase + (size_t)(ks * 32 + quad * 4 + i) * 64] = f2bf(tr0[i]);
            kTg[kbase + (size_t)(ks * 32 + 16 + quad * 4 + i) * 64] = f2bf(tr1[i]);
        }
#pragma unroll
        for (int st = 0; st < 4; ++st) {
            const size_t brow = (size_t)(rowbase + st * 16 + l15) * DKC + h * HKC + quad * 8 + ks * 32;
            const bf8v bk = *(const bf8v*)(kg + brow);
            kk[st] = mfma16(ak, bk, kk[st]);
            qk[st] = mfma16(aq, bk, qk[st]);
        }
    }
#pragma unroll
    for (int st = 0; st < 4; ++st)
#pragma unroll
        for (int i = 0; i < 4; ++i) {
            const int t = t0 + quad * 4 + i, s = st * 16 + l15;
            const float e = expf(gcs[t] - gcs[s]);
            T[t][s] = (s < t) ? bars[t] * e * kk[st][i] : 0.f;
            Pg[(size_t)CI * 4096 + t * 64 + s] = f2bf((s <= t) ? e * qk[st][i] : 0.f);
        }
    __syncthreads();
    if (wave == 0) {
        const int j = lane;
        Mm[0][j] = (j == 0) ? 1.f : 0.f;
        for (int t = 1; t < 64; ++t) {
            float acc = 0.f;
            for (int s = 0; s < t; ++s) acc += T[t][s] * Mm[s][j];
            Mm[t][j] = ((t == j) ? 1.f : 0.f) - acc;
        }
    }
    __syncthreads();
    for (int idx = tid; idx < 4096; idx += 256)
        Mg[(size_t)CI * 4096 + idx] = f2bf(Mm[idx >> 6][idx & 63]);
}

// ---------------- P2: inter-chunk recurrence, latency-hidden ----------------
// grid 256 blocks x 512 thr. XCD swizzle: bh = bid&15 (all 16 vs-blocks of one
// (b,h) share an XCD since dispatch is round-robin on bid%8). Register prefetch:
// k/v for chunk c+1 issued after phase1 of chunk c; M/P/q/kT issued at chunk top.
__global__ __launch_bounds__(512) void p2_kernel(const u16* __restrict__ qg,
                                                 const u16* __restrict__ kg,
                                                 const u16* __restrict__ vg,
                                                 const float* __restrict__ beta,
                                                 const float* __restrict__ gcg,
                                                 const u16* __restrict__ Mg,
                                                 const u16* __restrict__ Pg,
                                                 const u16* __restrict__ kTg,
                                                 u16* __restrict__ og) {
    __shared__ u16 SbT[2][32][264];   // S^T shadow [n][r], dbuf
    __shared__ u16 uT[32][72];
    __shared__ u16 vT[32][72];
    __shared__ u16 v2T[32][72];
    const int bid = blockIdx.x;
    const int bh = bid & 15, vs = bid >> 4;       // XCD-affinity swizzle
    const int h = bh & 3, b = bh >> 2;
    const int tid = threadIdx.x, lane = tid & 63, wave = tid >> 6;
    const int quad = lane >> 4, l15 = lane & 15;
    const int tw = wave >> 1, nw = wave & 1;
    const int t0 = tw * 16;
    const int ncol = nw * 16 + l15;
    for (int i = tid; i < 32 * 264; i += 512) ((u16*)SbT[0])[i] = 0;
    f32x4 S[4];
#pragma unroll
    for (int a = 0; a < 4; ++a) S[a] = (f32x4){0,0,0,0};

    // prefetch chunk 0: k frags + v
    bf8v kf[8]; u16 vf[4];
    {
        const int rowbase = b * TT;
        const size_t krow = (size_t)(rowbase + t0 + l15) * DKC + h * HKC + quad * 8;
#pragma unroll
        for (int ks = 0; ks < 8; ++ks) kf[ks] = *(const bf8v*)(kg + krow + ks * 32);
#pragma unroll
        for (int i = 0; i < 4; ++i)
            vf[i] = vg[(size_t)(rowbase + t0 + quad * 4 + i) * DVC + h * HVC + vs * 32 + ncol];
    }
    __syncthreads();

    for (int c = 0; c < NC; ++c) {
        const int cur = c & 1, nxt = cur ^ 1;
        const int CI = bh * NC + c;
        const int rowbase = b * TT + c * 64;
        // issue same-chunk loads (consumed 1-3 phases later)
        bf8v Mf[2], Pf[2], qf[8], kTf[8];
#pragma unroll
        for (int ks = 0; ks < 2; ++ks) {
            Mf[ks] = *(const bf8v*)(Mg + (size_t)CI * 4096 + (t0 + l15) * 64 + ks * 32 + quad * 8);
            Pf[ks] = *(const bf8v*)(Pg + (size_t)CI * 4096 + (t0 + l15) * 64 + ks * 32 + quad * 8);
        }
        const size_t qrow = (size_t)(rowbase + t0 + l15) * DKC + h * HKC + quad * 8;
#pragma unroll
        for (int ks = 0; ks < 8; ++ks) qf[ks] = *(const bf8v*)(qg + qrow + ks * 32);
#pragma unroll
        for (int a = 0; a < 4; ++a)
#pragma unroll
            for (int ks = 0; ks < 2; ++ks)
                kTf[a * 2 + ks] = *(const bf8v*)(kTg + (size_t)CI * 16384 +
                                                 (size_t)((tw * 4 + a) * 16 + l15) * 64 + ks * 32 + quad * 8);
        // per-lane row scalars
        const float gc63 = gcg[CI * 64 + 63];
        float bt[4], ga[4], gd[4];
#pragma unroll
        for (int i = 0; i < 4; ++i) {
            const int t = t0 + quad * 4 + i;
            bt[i] = beta[(size_t)(rowbase + t) * HH + h];
            const float gc = gcg[CI * 64 + t];
            ga[i] = expf(gc);
            gd[i] = expf(gc63 - gc);
        }
        // ---- phase1: u = bt*v - bt*ga*(k @ S) ----
        f32x4 ka0 = (f32x4){0,0,0,0}, ka1 = (f32x4){0,0,0,0};
        for (int ks = 0; ks < 8; ks += 2) {
            const bf8v bs0 = *(const bf8v*)(&SbT[cur][ncol][ks * 32 + quad * 8]);
            const bf8v bs1 = *(const bf8v*)(&SbT[cur][ncol][ks * 32 + 32 + quad * 8]);
            ka0 = mfma16(kf[ks], bs0, ka0);
            ka1 = mfma16(kf[ks + 1], bs1, ka1);
        }
        {
            ushort4 up; u16* upp = (u16*)&up;
#pragma unroll
            for (int i = 0; i < 4; ++i)
                upp[i] = f2bf(bt[i] * bf2f(vf[i]) - bt[i] * ga[i] * (ka0[i] + ka1[i]));
            *(ushort4*)(&uT[ncol][t0 + quad * 4]) = up;
        }
        // prefetch chunk c+1's k,v (kf/vf dead now; loads land during phases 2-4)
        if (c + 1 < NC) {
            const int rb2 = b * TT + (c + 1) * 64;
            const size_t krow2 = (size_t)(rb2 + t0 + l15) * DKC + h * HKC + quad * 8;
#pragma unroll
            for (int ks = 0; ks < 8; ++ks) kf[ks] = *(const bf8v*)(kg + krow2 + ks * 32);
#pragma unroll
            for (int i = 0; i < 4; ++i)
                vf[i] = vg[(size_t)(rb2 + t0 + quad * 4 + i) * DVC + h * HVC + vs * 32 + ncol];
        }
        __syncthreads();
        // ---- phase2: veff = M @ u ----
        f32x4 vacc = (f32x4){0,0,0,0};
        for (int ks = 0; ks < 2; ++ks) {
            const bf8v bu = *(const bf8v*)(&uT[ncol][ks * 32 + quad * 8]);
            vacc = mfma16(Mf[ks], bu, vacc);
        }
        {
            ushort4 vp, v2p; u16* vpp = (u16*)&vp; u16* v2pp = (u16*)&v2p;
#pragma unroll
            for (int i = 0; i < 4; ++i) {
                vpp[i] = f2bf(vacc[i]);
                v2pp[i] = f2bf(vacc[i] * gd[i]);
            }
            *(ushort4*)(&vT[ncol][t0 + quad * 4]) = vp;
            *(ushort4*)(&v2T[ncol][t0 + quad * 4]) = v2p;
        }
        __syncthreads();
        // ---- phase3: o = P@veff + ga*(q@S) ----
        f32x4 op_ = (f32x4){0,0,0,0};
        for (int ks = 0; ks < 2; ++ks) {
            const bf8v bv_ = *(const bf8v*)(&vT[ncol][ks * 32 + quad * 8]);
            op_ = mfma16(Pf[ks], bv_, op_);
        }
        f32x4 oq0 = (f32x4){0,0,0,0}, oq1 = (f32x4){0,0,0,0};
        for (int ks = 0; ks < 8; ks += 2) {
            const bf8v bs0 = *(const bf8v*)(&SbT[cur][ncol][ks * 32 + quad * 8]);
            const bf8v bs1 = *(const bf8v*)(&SbT[cur][ncol][ks * 32 + 32 + quad * 8]);
            oq0 = mfma16(qf[ks], bs0, oq0);
            oq1 = mfma16(qf[ks + 1], bs1, oq1);
        }
#pragma unroll
        for (int i = 0; i < 4; ++i) {
            const int t = t0 + quad * 4 + i;
            og[((size_t)bh * TT + c * 64 + t) * HVC + vs * 32 + ncol] =
                f2bf(op_[i] + ga[i] * (oq0[i] + oq1[i]));
        }
        // ---- phase4 (SbT dbuf): S = gC*S + kT @ (gd*veff) ----
        const float gC = expf(gc63);
#pragma unroll
        for (int a = 0; a < 4; ++a) {
            const int r0 = (tw * 4 + a) * 16;
            f32x4 acc = S[a] * gC;
            for (int ks = 0; ks < 2; ++ks) {
                const bf8v bv2 = *(const bf8v*)(&v2T[ncol][ks * 32 + quad * 8]);
                acc = mfma16(kTf[a * 2 + ks], bv2, acc);
            }
            S[a] = acc;
            ushort4 sp; u16* spp = (u16*)&sp;
#pragma unroll
            for (int i = 0; i < 4; ++i) spp[i] = f2bf(acc[i]);
            *(ushort4*)(&SbT[nxt][ncol][r0 + quad * 4]) = sp;
        }
        __syncthreads();
    }
}

// ---------------- RMSNorm + silu-gate; reads o (chunk layout), writes pg in place ----------------
__global__ __launch_bounds__(256) void gate_kernel(const u16* __restrict__ o,
                                                   u16* __restrict__ pg,
                                                   const float* __restrict__ norm_w) {
    const int row = blockIdx.x;
    const int b = row >> 11, t = row & 2047;
    const int tid = threadIdx.x;
    const int h = tid >> 6, lane = tid & 63;
    const size_t obase = ((size_t)(b * 4 + h) * TT + t) * HVC + lane * 4;
    const size_t pbase = (size_t)row * DVC + h * HVC + lane * 4;
    const ushort4 a4 = *(const ushort4*)&o[obase];
    const ushort4 b4 = *(const ushort4*)&o[obase + 256];
    float o1[4] = {bf2f(a4.x), bf2f(a4.y), bf2f(a4.z), bf2f(a4.w)};
    float o2[4] = {bf2f(b4.x), bf2f(b4.y), bf2f(b4.z), bf2f(b4.w)};
    float ss = 0.f;
#pragma unroll
    for (int j = 0; j < 4; ++j) ss += o1[j]*o1[j] + o2[j]*o2[j];
    for (int m = 32; m >= 1; m >>= 1) ss += __shfl_xor(ss, m, 64);
    const float rms = rsqrtf(ss * (1.0f / HVC) + 1e-5f);
    const float4 nw1 = *(const float4*)&norm_w[lane * 4];
    const float4 nw2 = *(const float4*)&norm_w[256 + lane * 4];
    const ushort4 g4a = *(const ushort4*)&pg[pbase];
    const ushort4 g4b = *(const ushort4*)&pg[pbase + 256];
    const float g1[4] = {bf2f(g4a.x), bf2f(g4a.y), bf2f(g4a.z), bf2f(g4a.w)};
    const float g2[4] = {bf2f(g4b.x), bf2f(g4b.y), bf2f(g4b.z), bf2f(g4b.w)};
    const float n1[4] = {nw1.x, nw1.y, nw1.z, nw1.w};
    const float n2[4] = {nw2.x, nw2.y, nw2.z, nw2.w};
    ushort4 r1, r2;
    u16* p1 = (u16*)&r1; u16* p2 = (u16*)&r2;
#pragma unroll
    for (int j = 0; j < 4; ++j) {
        p1[j] = f2bf(o1[j] * rms * n1[j] * g1[j] * sigmoidf_(g1[j]));
        p2[j] = f2bf(o2[j] * rms * n2[j] * g2[j] * sigmoidf_(g2[j]));
    }
    *(ushort4*)&pg[pbase] = r1;
    *(ushort4*)&pg[pbase + 256] = r2;
}

extern "C" void kernel_launch(void* const* d_in, const int* in_sizes, int n_in,
                              void* d_out, int out_size, void* d_ws, size_t ws_size,
                              hipStream_t stream) {
    const float* x       = (const float*)d_in[0];
    const float* ln_w    = (const float*)d_in[1];
    const float* ln_b    = (const float*)d_in[2];
    const float* Wq      = (const float*)d_in[3];
    const float* Wk      = (const float*)d_in[4];
    const float* Wv      = (const float*)d_in[5];
    const float* conv_q  = (const float*)d_in[6];
    const float* conv_k  = (const float*)d_in[7];
    const float* conv_v  = (const float*)d_in[8];
    const float* Wb      = (const float*)d_in[9];
    const float* Wa      = (const float*)d_in[10];
    const float* A_log   = (const float*)d_in[11];
    const float* dt_bias = (const float*)d_in[12];
    const float* Wg      = (const float*)d_in[13];
    const float* norm_w  = (const float*)d_in[14];
    const float* Wo      = (const float*)d_in[15];
    float* out = (float*)d_out;

    // Workspace layout: 124 MB peak; kTg (16MB) lives in d_out (dead until final GEMM)
    char* ws = (char*)d_ws;
    u16* normed = (u16*)(ws);                           // 16MB [0,16)
    u16* q      = (u16*)(ws + (16ull << 20));           // 16MB [16,32)
    u16* k      = (u16*)(ws + (32ull << 20));           // 16MB [32,48)
    u16* v      = (u16*)(ws + (48ull << 20));           // 32MB [48,80)
    u16* o      = (u16*)(ws + (80ull << 20));           // 32MB [80,112) chunk layout [B,H,T,HV]
    float* beta = (float*)(ws + (112ull << 20));              // 128KB
    float* gdec = (float*)(ws + (112ull << 20) + (128u<<10)); // 128KB
    float* gcg  = (float*)(ws + (112ull << 20) + (256u<<10)); // 128KB
    u16* halo   = (u16*)(ws + (113ull << 20));          // 3MB
    u16* Mg     = (u16*)(ws + (116ull << 20));          // 4MB
    u16* Pg     = (u16*)(ws + (120ull << 20));          // 4MB
    u16* pg     = q;                                    // 32MB (q+k region) after p2
    u16* WTe    = o;                                    // early weight-T scratch (o free until p2)
    u16* WgT    = Mg;                                   // Mg free after p2
    u16* WoT    = v;                                    // v free after p2
    u16* kTg    = (u16*)d_out;                          // 16MB k^T chunks; overwritten by final GEMM

    ln_kernel<<<RTOT, 256, 0, stream>>>(x, ln_w, ln_b, normed);

    wconv_kernel<<<dim3(DD / 32, DKC / 32), 256, 0, stream>>>(Wq, WTe, DD, DKC);
    gemm_mfma<0><<<dim3(DKC / 128, RTOT / 128), 256, 0, stream>>>(normed, WTe, q, RTOT, DKC, DD, nullptr);
    wconv_kernel<<<dim3(DD / 32, DKC / 32), 256, 0, stream>>>(Wk, WTe, DD, DKC);
    gemm_mfma<0><<<dim3(DKC / 128, RTOT / 128), 256, 0, stream>>>(normed, WTe, k, RTOT, DKC, DD, nullptr);
    wconv_kernel<<<dim3(DD / 32, DVC / 32), 256, 0, stream>>>(Wv, WTe, DD, DVC);
    gemm_mfma<0><<<dim3(DVC / 128, RTOT / 128), 256, 0, stream>>>(normed, WTe, v, RTOT, DVC, DD, nullptr);
    smallproj_kernel<<<RTOT, 256, 0, stream>>>(x, ln_w, ln_b, Wb, Wa, A_log, dt_bias, beta, gdec);

    halo_save<<<RTOT / TILE_CV, 256, 0, stream>>>(q, halo, DKC);
    conv_inplace<<<dim3(1, RTOT / TILE_CV), 256, 0, stream>>>(q, conv_q, halo, DKC);
    halo_save<<<RTOT / TILE_CV, 256, 0, stream>>>(k, halo, DKC);
    conv_inplace<<<dim3(1, RTOT / TILE_CV), 256, 0, stream>>>(k, conv_k, halo, DKC);
    halo_save<<<RTOT / TILE_CV, 256, 0, stream>>>(v, halo, DVC);
    conv_inplace<<<dim3(2, RTOT / TILE_CV), 256, 0, stream>>>(v, conv_v, halo, DVC);

    normqk_kernel<<<RTOT, 256, 0, stream>>>(q, k);

    p1a_kernel<<<BB * HH * NC, 256, 0, stream>>>(q, k, gdec, beta, Mg, Pg, kTg, gcg);
    p2_kernel<<<BB * HH * (HVC / 32), 512, 0, stream>>>(q, k, v, beta, gcg, Mg, Pg, kTg, o);

    // q,k dead -> pg; Mg dead -> WgT; v dead -> WoT
    wconv_kernel<<<dim3(DD / 32, DVC / 32), 256, 0, stream>>>(Wg, WgT, DD, DVC);
    gemm_mfma<0><<<dim3(DVC / 128, RTOT / 128), 256, 0, stream>>>(normed, WgT, pg, RTOT, DVC, DD, nullptr);

    gate_kernel<<<RTOT, 256, 0, stream>>>(o, pg, norm_w);

    wconv_kernel<<<dim3(DVC / 32, DD / 32), 256, 0, stream>>>(Wo, WoT, DVC, DD);
    gemm_mfma<1><<<dim3(DD / 128, RTOT / 128), 256, 0, stream>>>(pg, WoT, out, RTOT, DD, DVC, x);
}